// Round 1
// baseline (203.935 us; speedup 1.0000x reference)
//
#include <hip/hip_runtime.h>

// Problem constants
#define B_SZ   8
#define T_SEQ  2048
#define C_DIM  1024
#define H_DIM  128

typedef _Float16 half8  __attribute__((ext_vector_type(8)));
typedef _Float16 half4_t __attribute__((ext_vector_type(4)));
typedef float    f32x4  __attribute__((ext_vector_type(4)));

#define MFMA(a, b, c) __builtin_amdgcn_mfma_f32_16x16x32_f16(a, b, c, 0, 0, 0)

// ---------------------------------------------------------------------------
// prep: W [C][H] fp32  ->  WT [H][C] half   (3 weights)
// grid (512, 3) x 256
// ---------------------------------------------------------------------------
__global__ __launch_bounds__(256) void prep_kernel(
    const float* __restrict__ Wk, const float* __restrict__ Wq,
    const float* __restrict__ Wv, _Float16* __restrict__ WT_all)
{
    const int w = blockIdx.y;
    const float* W = (w == 0) ? Wk : (w == 1) ? Wq : Wv;
    _Float16* dst = WT_all + (size_t)w * (C_DIM * H_DIM);
    int tid = blockIdx.x * 256 + threadIdx.x;        // 0..131071
    int c = tid >> 7;                                 // /H_DIM
    int h = tid & (H_DIM - 1);
    dst[(size_t)h * C_DIM + c] = (_Float16)W[tid];    // coalesced read, scattered 2B write (tiny)
}

// ---------------------------------------------------------------------------
// proj: out[m][n] = sum_k x[m][k] * W[k][n], M=16384 K=1024 N=128, f16 MFMA.
// grid (3, 128) x 256  (blockIdx.x = weight -> the 3 reads of an x tile are
// temporally adjacent so L3 absorbs the re-reads).
// w==0 -> k [B*T][H], w==1 -> q [B*T][H], w==2 -> vT [B][H][T] (transposed!)
// ---------------------------------------------------------------------------
__global__ __launch_bounds__(256) void proj_kernel(
    const float* __restrict__ x, const _Float16* __restrict__ WT_all,
    _Float16* __restrict__ q, _Float16* __restrict__ k, _Float16* __restrict__ vT)
{
    __shared__ _Float16 xs[128][72];    // 64 k + 8 pad (144B stride, 16B aligned)
    __shared__ _Float16 wsh[128][72];

    const int w  = blockIdx.x;
    const int m0 = blockIdx.y * 128;
    const _Float16* WT = WT_all + (size_t)w * (C_DIM * H_DIM);

    const int t    = threadIdx.x;
    const int wave = t >> 6, lane = t & 63;
    const int quad = lane >> 4, l15 = lane & 15;
    const int wm = (wave >> 1) * 64;   // wave m-offset
    const int wn = (wave & 1) * 64;    // wave n-offset

    f32x4 acc[4][4] = {};

    for (int k0 = 0; k0 < C_DIM; k0 += 64) {
        __syncthreads();
        // stage x tile: 128 rows x 64 k, fp32 -> half
        {
            const int row_ = t >> 4, col = (t & 15) * 4;
            #pragma unroll
            for (int p = 0; p < 8; ++p) {
                int row = p * 16 + row_;
                float4 f = *(const float4*)(x + (size_t)(m0 + row) * C_DIM + k0 + col);
                half4_t hv = { (_Float16)f.x, (_Float16)f.y, (_Float16)f.z, (_Float16)f.w };
                *(half4_t*)(&xs[row][col]) = hv;
            }
        }
        // stage WT tile: 128 n-rows x 64 k (already half, contiguous)
        {
            const int row_ = t >> 3, col = (t & 7) * 8;
            #pragma unroll
            for (int p = 0; p < 4; ++p) {
                int row = p * 32 + row_;
                *(half8*)(&wsh[row][col]) = *(const half8*)(WT + (size_t)row * C_DIM + k0 + col);
            }
        }
        __syncthreads();
        #pragma unroll
        for (int kb = 0; kb < 2; ++kb) {
            half8 af[4], bf[4];
            #pragma unroll
            for (int i = 0; i < 4; ++i)
                af[i] = *(const half8*)(&xs[wm + i * 16 + l15][kb * 32 + quad * 8]);
            #pragma unroll
            for (int i = 0; i < 4; ++i)
                bf[i] = *(const half8*)(&wsh[wn + i * 16 + l15][kb * 32 + quad * 8]);
            #pragma unroll
            for (int i = 0; i < 4; ++i)
                #pragma unroll
                for (int j = 0; j < 4; ++j)
                    acc[i][j] = MFMA(af[i], bf[j], acc[i][j]);
        }
    }

    // epilogue: C layout row = quad*4 + r, col = l15 (per 16x16 tile)
    if (w != 2) {
        _Float16* outN = (w == 0) ? k : q;
        #pragma unroll
        for (int i = 0; i < 4; ++i) {
            int row = m0 + wm + i * 16 + quad * 4;
            #pragma unroll
            for (int j = 0; j < 4; ++j) {
                int col = wn + j * 16 + l15;
                #pragma unroll
                for (int r = 0; r < 4; ++r)
                    outN[(size_t)(row + r) * H_DIM + col] = (_Float16)acc[i][j][r];
            }
        }
    } else {
        // v transposed: vT[b][h][t]; 4 consecutive t per (i,j) -> 8B store
        #pragma unroll
        for (int i = 0; i < 4; ++i) {
            int grow = m0 + wm + i * 16 + quad * 4;      // flattened b*T + t
            int bb = grow >> 11, tp = grow & (T_SEQ - 1);
            #pragma unroll
            for (int j = 0; j < 4; ++j) {
                int h = wn + j * 16 + l15;
                half4_t hv = { (_Float16)acc[i][j][0], (_Float16)acc[i][j][1],
                               (_Float16)acc[i][j][2], (_Float16)acc[i][j][3] };
                *(half4_t*)(vT + ((size_t)bb * H_DIM + h) * T_SEQ + tp) = hv;
            }
        }
    }
}

// ---------------------------------------------------------------------------
// attn: flash attention, causal. qtile=32 (2 waves x 16-row strip), kv tile 64.
// grid (64, 8) x 128; qt = 63 - blockIdx.x so long (diagonal-heavy) blocks
// dispatch first -> balanced makespan.
// ---------------------------------------------------------------------------
__global__ __launch_bounds__(128) void attn_kernel(
    const _Float16* __restrict__ q, const _Float16* __restrict__ k,
    const _Float16* __restrict__ vT, float* __restrict__ out)
{
    __shared__ _Float16 ks [64][136];   // keys x H, pad 8 (272B stride)
    __shared__ _Float16 vts[128][72];   // H x keys, pad 8 (144B stride)
    __shared__ _Float16 ps [2][16][72]; // per-wave P strip (C->A layout round-trip)

    const int qt = 63 - blockIdx.x;
    const int b  = blockIdx.y;
    const int t  = threadIdx.x;
    const int wave = t >> 6, lane = t & 63;
    const int quad = lane >> 4, l15 = lane & 15;
    const int qrow0 = qt * 32 + wave * 16;   // this wave's strip base row

    const _Float16* qb = q  + (size_t)b * T_SEQ * H_DIM;
    const _Float16* kp = k  + (size_t)b * T_SEQ * H_DIM;
    const _Float16* vp = vT + (size_t)b * H_DIM * T_SEQ;

    // Q fragments in registers (A layout): lane holds row m = l15, k = kb*32 + quad*8 + j
    half8 aq[4];
    #pragma unroll
    for (int i = 0; i < 4; ++i)
        aq[i] = *(const half8*)(qb + (size_t)(qrow0 + l15) * H_DIM + i * 32 + quad * 8);

    f32x4 accO[8] = {};
    float mrun[4], lrun[4];
    #pragma unroll
    for (int r = 0; r < 4; ++r) { mrun[r] = -3.0e38f; lrun[r] = 0.0f; }

    const int ntiles = (qt * 32 + 31) / 64 + 1;
    const float scale = 0.088388347648318447f;   // 1/sqrt(128)

    for (int kt = 0; kt < ntiles; ++kt) {
        const int kv0 = kt * 64;
        __syncthreads();
        // stage K tile [64][128]
        {
            const int row_ = t >> 4, seg = t & 15;
            #pragma unroll
            for (int p = 0; p < 8; ++p) {
                int row = p * 8 + row_;
                *(half8*)(&ks[row][seg * 8]) =
                    *(const half8*)(kp + (size_t)(kv0 + row) * H_DIM + seg * 8);
            }
        }
        // stage V^T tile [128][64] (contiguous from vT global)
        {
            const int h_ = t >> 3, seg = t & 7;
            #pragma unroll
            for (int p = 0; p < 8; ++p) {
                int h = p * 16 + h_;
                *(half8*)(&vts[h][seg * 8]) =
                    *(const half8*)(vp + (size_t)h * T_SEQ + kv0 + seg * 8);
            }
        }
        __syncthreads();

        // S = Q K^T : strip [16 x 64], 4 n-tiles
        f32x4 sacc[4] = {};
        #pragma unroll
        for (int kbi = 0; kbi < 4; ++kbi) {
            #pragma unroll
            for (int nt = 0; nt < 4; ++nt) {
                half8 bf = *(const half8*)(&ks[nt * 16 + l15][kbi * 32 + quad * 8]);
                sacc[nt] = MFMA(aq[kbi], bf, sacc[nt]);
            }
        }

        // scale + causal mask (reference: mask->-inf then scale == scale then -big)
        float sv[4][4];
        if (kv0 + 63 <= qrow0) {                 // whole tile strictly below diagonal
            #pragma unroll
            for (int nt = 0; nt < 4; ++nt)
                #pragma unroll
                for (int r = 0; r < 4; ++r)
                    sv[nt][r] = sacc[nt][r] * scale;
        } else {
            #pragma unroll
            for (int nt = 0; nt < 4; ++nt) {
                int key = kv0 + nt * 16 + l15;
                #pragma unroll
                for (int r = 0; r < 4; ++r) {
                    int qr = qrow0 + quad * 4 + r;
                    sv[nt][r] = (key <= qr) ? sacc[nt][r] * scale : -1.0e30f;
                }
            }
        }

        // online softmax; row r lives in lanes sharing this quad -> 16-lane reduce
        float mnew[4], alpha[4], rsum[4];
        #pragma unroll
        for (int r = 0; r < 4; ++r) {
            float rm = fmaxf(fmaxf(sv[0][r], sv[1][r]), fmaxf(sv[2][r], sv[3][r]));
            rm = fmaxf(rm, __shfl_xor(rm, 1));
            rm = fmaxf(rm, __shfl_xor(rm, 2));
            rm = fmaxf(rm, __shfl_xor(rm, 4));
            rm = fmaxf(rm, __shfl_xor(rm, 8));
            mnew[r]  = fmaxf(mrun[r], rm);
            alpha[r] = __expf(mrun[r] - mnew[r]);
            mrun[r]  = mnew[r];
            rsum[r]  = 0.0f;
        }
        #pragma unroll
        for (int nt = 0; nt < 4; ++nt)
            #pragma unroll
            for (int r = 0; r < 4; ++r) {
                float p = __expf(sv[nt][r] - mnew[r]);
                rsum[r] += p;
                ps[wave][quad * 4 + r][nt * 16 + l15] = (_Float16)p;   // C layout -> LDS
            }
        #pragma unroll
        for (int r = 0; r < 4; ++r) {
            rsum[r] += __shfl_xor(rsum[r], 1);
            rsum[r] += __shfl_xor(rsum[r], 2);
            rsum[r] += __shfl_xor(rsum[r], 4);
            rsum[r] += __shfl_xor(rsum[r], 8);
            lrun[r] = lrun[r] * alpha[r] + rsum[r];
        }
        #pragma unroll
        for (int nt = 0; nt < 8; ++nt)
            #pragma unroll
            for (int r = 0; r < 4; ++r)
                accO[nt][r] *= alpha[r];

        __syncthreads();   // ps write -> read ordering (and cheap with 2 waves)

        // O += P V : read P back in A layout, V^T rows give B fragments
        half8 pf0 = *(const half8*)(&ps[wave][l15][quad * 8]);
        half8 pf1 = *(const half8*)(&ps[wave][l15][32 + quad * 8]);
        #pragma unroll
        for (int nt = 0; nt < 8; ++nt) {
            half8 vf0 = *(const half8*)(&vts[nt * 16 + l15][quad * 8]);
            half8 vf1 = *(const half8*)(&vts[nt * 16 + l15][32 + quad * 8]);
            accO[nt] = MFMA(pf0, vf0, accO[nt]);
            accO[nt] = MFMA(pf1, vf1, accO[nt]);
        }
    }

    // epilogue: out fp32 [B][T][H]
    float invl[4];
    #pragma unroll
    for (int r = 0; r < 4; ++r) invl[r] = 1.0f / lrun[r];
    #pragma unroll
    for (int nt = 0; nt < 8; ++nt)
        #pragma unroll
        for (int r = 0; r < 4; ++r)
            out[((size_t)b * T_SEQ + qrow0 + quad * 4 + r) * H_DIM + nt * 16 + l15]
                = accO[nt][r] * invl[r];
}

// ---------------------------------------------------------------------------
extern "C" void kernel_launch(void* const* d_in, const int* in_sizes, int n_in,
                              void* d_out, int out_size, void* d_ws, size_t ws_size,
                              hipStream_t stream)
{
    const float* x  = (const float*)d_in[0];
    const float* Wk = (const float*)d_in[1];
    const float* Wq = (const float*)d_in[2];
    const float* Wv = (const float*)d_in[3];
    float* out = (float*)d_out;

    _Float16* ws    = (_Float16*)d_ws;
    const size_t NQKV = (size_t)B_SZ * T_SEQ * H_DIM;   // 2097152
    _Float16* q_ws  = ws;
    _Float16* k_ws  = ws + NQKV;
    _Float16* vT_ws = ws + 2 * NQKV;
    _Float16* wt_ws = ws + 3 * NQKV;                    // 3 * 131072 halfs

    prep_kernel<<<dim3(512, 3), 256, 0, stream>>>(Wk, Wq, Wv, wt_ws);
    proj_kernel<<<dim3(3, 128), 256, 0, stream>>>(x, wt_ws, q_ws, k_ws, vT_ws);
    attn_kernel<<<dim3(64, 8), 128, 0, stream>>>(q_ws, k_ws, vT_ws, out);
}